// Round 6
// baseline (264.115 us; speedup 1.0000x reference)
//
#include <hip/hip_runtime.h>

#define N_NODES 100000
#define N_EDGES 1600000
#define NBKT 391          // buckets of 256 rows (391*256 = 100096 >= N)
#define BCAP 6144         // per-bucket LDS staging capacity (mean 4096, sigma ~64)
#define NPW 8             // nodes per wave in fused agg2_out

// ---------------- Pass A: bucket histogram (LDS-reduced) ----------------
__global__ __launch_bounds__(256) void bhist_kernel(const int* __restrict__ row,
                                                    unsigned* __restrict__ bucketcnt, int E) {
    __shared__ unsigned h[NBKT];
    int t = threadIdx.x;
    for (int i = t; i < NBKT; i += 256) h[i] = 0;
    __syncthreads();
    for (int i = blockIdx.x * 256 + t; i < E; i += NBKT * 256)
        atomicAdd(&h[row[i] >> 8], 1u);
    __syncthreads();
    for (int i = t; i < NBKT; i += 256)
        if (h[i]) atomicAdd(&bucketcnt[i], h[i]);
}

// ---------------- Pass B: exclusive scan of 391 bucket counts ----------------
__global__ __launch_bounds__(512) void bscan_kernel(const unsigned* __restrict__ bucketcnt,
                                                    unsigned* __restrict__ bucketbase,
                                                    unsigned* __restrict__ bucketcur) {
    __shared__ unsigned lds[512];
    int t = threadIdx.x;
    unsigned v = (t < NBKT) ? bucketcnt[t] : 0u;
    lds[t] = v;
    __syncthreads();
    for (int s = 1; s < 512; s <<= 1) {
        unsigned add = (t >= s) ? lds[t - s] : 0u;
        __syncthreads();
        lds[t] += add;
        __syncthreads();
    }
    if (t < NBKT) { unsigned b = lds[t] - v; bucketbase[t] = b; bucketcur[t] = b; }
}

// ---------------- Pass C: block-local multi-split partition ----------------
__global__ __launch_bounds__(256) void part_kernel(const int* __restrict__ row,
                                                   const int* __restrict__ col,
                                                   unsigned* __restrict__ bucketcur,
                                                   unsigned* __restrict__ entries, int E) {
    __shared__ unsigned h[NBKT];
    int t = threadIdx.x;
    for (int i = t; i < NBKT; i += 256) h[i] = 0;
    __syncthreads();
    int base_i = blockIdx.x * 4096;
    int r[16], c[16];
#pragma unroll
    for (int k = 0; k < 16; ++k) {
        int i = base_i + k * 256 + t;
        if (i < E) {
            r[k] = row[i]; c[k] = col[i];
            atomicAdd(&h[r[k] >> 8], 1u);
        } else r[k] = -1;
    }
    __syncthreads();
    for (int i = t; i < NBKT; i += 256) {
        unsigned cnt = h[i];
        if (cnt) h[i] = atomicAdd(&bucketcur[i], cnt);   // h becomes running cursor
    }
    __syncthreads();
#pragma unroll
    for (int k = 0; k < 16; ++k) {
        if (r[k] >= 0) {
            unsigned slot = atomicAdd(&h[r[k] >> 8], 1u);
            entries[slot] = ((unsigned)(r[k] & 255) << 24) | (unsigned)c[k];
        }
    }
}

// ---------------- Pass D: per-bucket CSR finalize ----------------
__global__ __launch_bounds__(1024) void csr_kernel(const unsigned* __restrict__ bucketbase,
                                                   const unsigned* __restrict__ bucketcnt,
                                                   unsigned* __restrict__ entries,
                                                   uint2* __restrict__ rs_deg,
                                                   float* __restrict__ dinv, int n) {
    __shared__ unsigned se[BCAP];
    __shared__ unsigned cnt[256];
    __shared__ unsigned sc[256];
    __shared__ unsigned cur[256];
    int t = threadIdx.x, b = blockIdx.x;
    if (t < 256) cnt[t] = 0;
    __syncthreads();
    unsigned base = bucketbase[b], m = bucketcnt[b];
    for (unsigned j = t; j < m; j += 1024) {
        unsigned e = entries[base + j];
        if (j < BCAP) se[j] = e;
        atomicAdd(&cnt[e >> 24], 1u);
    }
    __syncthreads();
    if (t < 256) sc[t] = cnt[t];
    __syncthreads();
    for (int s = 1; s < 256; s <<= 1) {
        unsigned a = (t < 256 && t >= s) ? sc[t - s] : 0u;
        __syncthreads();
        if (t < 256) sc[t] += a;
        __syncthreads();
    }
    if (t < 256) {
        unsigned excl = sc[t] - cnt[t];
        cur[t] = excl;
        int node = b * 256 + t;
        if (node < n) {
            rs_deg[node] = make_uint2(base + excl, cnt[t]);
            dinv[node] = cnt[t] ? rsqrtf((float)cnt[t]) : 0.f;
        }
    }
    __syncthreads();
    for (unsigned j = t; j < m; j += 1024) {
        unsigned e = (j < BCAP) ? se[j] : entries[base + j];
        unsigned pos = atomicAdd(&cur[e >> 24], 1u);
        entries[base + pos] = e & 0xFFFFFF;
    }
}

// ---------------- proj1 v2: register-blocked; P0 = x@W1[0], P1s = (x@W1[1])*dinv ----
__global__ __launch_bounds__(256) void proj1_kernel(const float* __restrict__ x,
                                                    const float* __restrict__ W1,
                                                    const float* __restrict__ dinv,
                                                    float* __restrict__ P0,
                                                    float* __restrict__ P1s, int n) {
    __shared__ float xs[64 * 132];
    __shared__ float wt[32 * 132];
    int t = threadIdx.x;
    int base = blockIdx.x * 64;
    for (int idx = t; idx < 32 * 128; idx += 256) {
        int j = idx >> 7, k = idx & 127;
        int r = (j & 7) * 4 + (j >> 3);
        wt[r * 132 + k] = W1[((j >> 4) ? 2048 : 0) + k * 16 + (j & 15)];
    }
    for (int idx = t; idx < 2048; idx += 256) {
        int row = idx >> 5, c4 = idx & 31;
        int node = base + row;
        float4 v = make_float4(0.f, 0.f, 0.f, 0.f);
        if (node < n) v = *(const float4*)&x[(size_t)node * 128 + c4 * 4];
        *(float4*)&xs[row * 132 + c4 * 4] = v;
    }
    __syncthreads();
    int nl = t >> 2, q = t & 3;
    int node = base + nl;
    float acc[8] = {0.f, 0.f, 0.f, 0.f, 0.f, 0.f, 0.f, 0.f};
    const float* xr = xs + nl * 132;
    const float* wb = wt + q * 132;
#pragma unroll 4
    for (int kb = 0; kb < 32; ++kb) {
        float4 xv = *(const float4*)&xr[kb * 4];
#pragma unroll
        for (int jj = 0; jj < 8; ++jj) {
            float4 wv = *(const float4*)&wb[jj * 4 * 132 + kb * 4];
            acc[jj] += xv.x * wv.x + xv.y * wv.y + xv.z * wv.z + xv.w * wv.w;
        }
    }
    if (node >= n) return;
    if (q < 2) {
        *(float4*)&P0[(size_t)node * 16 + q * 8]     = make_float4(acc[0], acc[1], acc[2], acc[3]);
        *(float4*)&P0[(size_t)node * 16 + q * 8 + 4] = make_float4(acc[4], acc[5], acc[6], acc[7]);
    } else {
        float dr = dinv[node];
        int o = (q - 2) * 8;
        *(float4*)&P1s[(size_t)node * 16 + o]     = make_float4(acc[0]*dr, acc[1]*dr, acc[2]*dr, acc[3]*dr);
        *(float4*)&P1s[(size_t)node * 16 + o + 4] = make_float4(acc[4]*dr, acc[5]*dr, acc[6]*dr, acc[7]*dr);
    }
}

// ---------------- agg1: wave-per-node segment sum + relu epilogue ----------------
__global__ __launch_bounds__(256) void agg1_kernel(const uint2* __restrict__ rs_deg,
                                                   const unsigned* __restrict__ ecol,
                                                   const float* __restrict__ dinv,
                                                   const float* __restrict__ P1s,
                                                   const float* __restrict__ b1,
                                                   float* __restrict__ H,   // in: P0, out: h
                                                   float* __restrict__ HS, int n) {
    int wave = threadIdx.x >> 6, lane = threadIdx.x & 63;
    int node = blockIdx.x * 4 + wave;
    if (node >= n) return;
    int f = lane & 15, slot = lane >> 4;
    uint2 rd = rs_deg[node];
    float s = 0.f;
    unsigned j = slot, d = rd.y;
    for (; j + 12 < d; j += 16) {
        unsigned c0 = ecol[rd.x + j];
        unsigned c1 = ecol[rd.x + j + 4];
        unsigned c2 = ecol[rd.x + j + 8];
        unsigned c3 = ecol[rd.x + j + 12];
        s += P1s[(size_t)c0 * 16 + f] + P1s[(size_t)c1 * 16 + f]
           + P1s[(size_t)c2 * 16 + f] + P1s[(size_t)c3 * 16 + f];
    }
    for (; j < d; j += 4) s += P1s[(size_t)ecol[rd.x + j] * 16 + f];
    s += __shfl_xor(s, 16);
    s += __shfl_xor(s, 32);
    if (slot == 0) {
        float dr = dinv[node];
        float v = H[(size_t)node * 16 + f] - dr * s + b1[f];
        v = fmaxf(v, 0.f);
        H[(size_t)node * 16 + f] = v;
        HS[(size_t)node * 16 + f] = v * dr;
    }
}

// ---------------- agg2 + out-proj + log_softmax, fused v2 ----------------
// W2 columns held in 64 VGPRs per wave, amortized over NPW nodes.
// t2 broadcast via per-wave LDS row (DS ops are wave-in-order; no barrier).
__global__ __launch_bounds__(256) void agg2_out_kernel(const uint2* __restrict__ rs_deg,
                                                       const unsigned* __restrict__ ecol,
                                                       const float* __restrict__ dinv,
                                                       const float* __restrict__ HS,
                                                       const float* __restrict__ H,
                                                       const float* __restrict__ W2,
                                                       const float* __restrict__ b2,
                                                       float* __restrict__ out, int n) {
    __shared__ float t2s[4][20];          // one 16-float row per wave (80B stride, 16B-aligned)
    int wl = threadIdx.x >> 6, lane = threadIdx.x & 63;
    int wid = blockIdx.x * 4 + wl;        // global wave id
    int f = lane & 15, slot = lane >> 4;

    // preload this wave's two W2 columns (j=lane, j=lane+64) for both terms
    float w00[16], w01[16], w10[16], w11[16];
#pragma unroll
    for (int k = 0; k < 16; ++k) {
        w00[k] = W2[k * 128 + lane];
        w01[k] = W2[2048 + k * 128 + lane];
        w10[k] = W2[k * 128 + lane + 64];
        w11[k] = W2[2048 + k * 128 + lane + 64];
    }
    float bb0 = b2[lane], bb1 = b2[lane + 64];

    for (int i = 0; i < NPW; ++i) {
        int node = wid * NPW + i;
        if (node >= n) return;            // uniform within wave
        uint2 rd = rs_deg[node];
        float s = 0.f;
        unsigned j = slot, d = rd.y;
        for (; j + 12 < d; j += 16) {
            unsigned c0 = ecol[rd.x + j];
            unsigned c1 = ecol[rd.x + j + 4];
            unsigned c2 = ecol[rd.x + j + 8];
            unsigned c3 = ecol[rd.x + j + 12];
            s += HS[(size_t)c0 * 16 + f] + HS[(size_t)c1 * 16 + f]
               + HS[(size_t)c2 * 16 + f] + HS[(size_t)c3 * 16 + f];
        }
        for (; j < d; j += 4) s += HS[(size_t)ecol[rd.x + j] * 16 + f];
        s += __shfl_xor(s, 16);
        s += __shfl_xor(s, 32);
        // all lanes hold the f-total; lanes 0-15 publish t2 to this wave's LDS row
        if (slot == 0) t2s[wl][f] = -dinv[node] * s;
        __builtin_amdgcn_wave_barrier();  // scheduling fence only; DS is wave-in-order
        float4 t0 = *(const float4*)&t2s[wl][0];
        float4 t1 = *(const float4*)&t2s[wl][4];
        float4 t2v = *(const float4*)&t2s[wl][8];
        float4 t3 = *(const float4*)&t2s[wl][12];
        const float* hp = H + (size_t)node * 16;
        float4 h0 = *(const float4*)&hp[0];
        float4 h1 = *(const float4*)&hp[4];
        float4 h2 = *(const float4*)&hp[8];
        float4 h3 = *(const float4*)&hp[12];
        float hv[16] = {h0.x,h0.y,h0.z,h0.w, h1.x,h1.y,h1.z,h1.w,
                        h2.x,h2.y,h2.z,h2.w, h3.x,h3.y,h3.z,h3.w};
        float tv[16] = {t0.x,t0.y,t0.z,t0.w, t1.x,t1.y,t1.z,t1.w,
                        t2v.x,t2v.y,t2v.z,t2v.w, t3.x,t3.y,t3.z,t3.w};
        float o0 = bb0, o1 = bb1;
#pragma unroll
        for (int k = 0; k < 16; ++k) {
            o0 += hv[k] * w00[k] + tv[k] * w01[k];
            o1 += hv[k] * w10[k] + tv[k] * w11[k];
        }
        float mx = fmaxf(o0, o1);
#pragma unroll
        for (int st = 1; st < 64; st <<= 1) mx = fmaxf(mx, __shfl_xor(mx, st));
        float ssum = expf(o0 - mx) + expf(o1 - mx);
#pragma unroll
        for (int st = 1; st < 64; st <<= 1) ssum += __shfl_xor(ssum, st);
        float lse = mx + logf(ssum);
        out[(size_t)node * 128 + lane]      = o0 - lse;
        out[(size_t)node * 128 + lane + 64] = o1 - lse;
    }
}

extern "C" void kernel_launch(void* const* d_in, const int* in_sizes, int n_in,
                              void* d_out, int out_size, void* d_ws, size_t ws_size,
                              hipStream_t stream) {
    const float* x  = (const float*)d_in[0];
    const int*   ei = (const int*)d_in[1];
    const float* W1 = (const float*)d_in[2];
    const float* b1 = (const float*)d_in[3];
    const float* W2 = (const float*)d_in[4];
    const float* b2 = (const float*)d_in[5];
    float* out = (float*)d_out;

    const int n = N_NODES, E = N_EDGES;
    const int* row = ei;
    const int* col = ei + E;

    // workspace layout (4B units); NPAD = 391*256 = 100096
    const size_t NPAD = 100096;
    unsigned* bucketcnt  = (unsigned*)d_ws;              // 512
    unsigned* bucketbase = bucketcnt + 512;              // 512
    unsigned* bucketcur  = bucketbase + 512;             // 512
    uint2*    rs_deg     = (uint2*)(bucketcur + 512);    // NPAD uint2
    float*    dinv       = (float*)(rs_deg + NPAD);      // NPAD
    unsigned* entries    = (unsigned*)(dinv + NPAD);     // E (packed, then col-only CSR)
    float*    P0         = (float*)(entries + E);        // NPAD*16 (becomes H in-place)
    float*    P1s        = P0 + NPAD * 16;               // NPAD*16
    float*    HS         = P1s + NPAD * 16;              // NPAD*16

    hipMemsetAsync(bucketcnt, 0, 512 * sizeof(unsigned), stream);

    bhist_kernel<<<NBKT, 256, 0, stream>>>(row, bucketcnt, E);
    bscan_kernel<<<1, 512, 0, stream>>>(bucketcnt, bucketbase, bucketcur);
    part_kernel<<<NBKT, 256, 0, stream>>>(row, col, bucketcur, entries, E);
    csr_kernel<<<NBKT, 1024, 0, stream>>>(bucketbase, bucketcnt, entries, rs_deg, dinv, n);
    proj1_kernel<<<(n + 63) / 64, 256, 0, stream>>>(x, W1, dinv, P0, P1s, n);
    agg1_kernel<<<(n + 3) / 4, 256, 0, stream>>>(rs_deg, entries, dinv, P1s, b1, P0, HS, n);
    int waves = (n + NPW - 1) / NPW;
    agg2_out_kernel<<<(waves + 3) / 4, 256, 0, stream>>>(rs_deg, entries, dinv, HS, P0, W2, b2, out, n);
}

// Round 7
// 216.041 us; speedup vs baseline: 1.2225x; 1.2225x over previous
//
#include <hip/hip_runtime.h>

#define N_NODES 100000
#define N_EDGES 1600000
#define NBKT 391          // buckets of 256 rows (391*256 = 100096 >= N)
#define BCAP 6144         // per-bucket LDS staging capacity (mean 4096, sigma ~64)

// ---------------- Pass A: bucket histogram (LDS-reduced) ----------------
__global__ __launch_bounds__(256) void bhist_kernel(const int* __restrict__ row,
                                                    unsigned* __restrict__ bucketcnt, int E) {
    __shared__ unsigned h[NBKT];
    int t = threadIdx.x;
    for (int i = t; i < NBKT; i += 256) h[i] = 0;
    __syncthreads();
    for (int i = blockIdx.x * 256 + t; i < E; i += NBKT * 256)
        atomicAdd(&h[row[i] >> 8], 1u);
    __syncthreads();
    for (int i = t; i < NBKT; i += 256)
        if (h[i]) atomicAdd(&bucketcnt[i], h[i]);
}

// ---------------- Pass B: exclusive scan of 391 bucket counts ----------------
__global__ __launch_bounds__(512) void bscan_kernel(const unsigned* __restrict__ bucketcnt,
                                                    unsigned* __restrict__ bucketbase,
                                                    unsigned* __restrict__ bucketcur) {
    __shared__ unsigned lds[512];
    int t = threadIdx.x;
    unsigned v = (t < NBKT) ? bucketcnt[t] : 0u;
    lds[t] = v;
    __syncthreads();
    for (int s = 1; s < 512; s <<= 1) {
        unsigned add = (t >= s) ? lds[t - s] : 0u;
        __syncthreads();
        lds[t] += add;
        __syncthreads();
    }
    if (t < NBKT) { unsigned b = lds[t] - v; bucketbase[t] = b; bucketcur[t] = b; }
}

// ---------------- Pass C: block-local multi-split partition ----------------
__global__ __launch_bounds__(256) void part_kernel(const int* __restrict__ row,
                                                   const int* __restrict__ col,
                                                   unsigned* __restrict__ bucketcur,
                                                   unsigned* __restrict__ entries, int E) {
    __shared__ unsigned h[NBKT];
    int t = threadIdx.x;
    for (int i = t; i < NBKT; i += 256) h[i] = 0;
    __syncthreads();
    int base_i = blockIdx.x * 4096;
    int r[16], c[16];
#pragma unroll
    for (int k = 0; k < 16; ++k) {
        int i = base_i + k * 256 + t;
        if (i < E) {
            r[k] = row[i]; c[k] = col[i];
            atomicAdd(&h[r[k] >> 8], 1u);
        } else r[k] = -1;
    }
    __syncthreads();
    for (int i = t; i < NBKT; i += 256) {
        unsigned cnt = h[i];
        if (cnt) h[i] = atomicAdd(&bucketcur[i], cnt);   // h becomes running cursor
    }
    __syncthreads();
#pragma unroll
    for (int k = 0; k < 16; ++k) {
        if (r[k] >= 0) {
            unsigned slot = atomicAdd(&h[r[k] >> 8], 1u);
            entries[slot] = ((unsigned)(r[k] & 255) << 24) | (unsigned)c[k];
        }
    }
}

// ---------------- Pass D: per-bucket CSR finalize ----------------
__global__ __launch_bounds__(1024) void csr_kernel(const unsigned* __restrict__ bucketbase,
                                                   const unsigned* __restrict__ bucketcnt,
                                                   unsigned* __restrict__ entries,
                                                   uint2* __restrict__ rs_deg,
                                                   float* __restrict__ dinv, int n) {
    __shared__ unsigned se[BCAP];
    __shared__ unsigned cnt[256];
    __shared__ unsigned sc[256];
    __shared__ unsigned cur[256];
    int t = threadIdx.x, b = blockIdx.x;
    if (t < 256) cnt[t] = 0;
    __syncthreads();
    unsigned base = bucketbase[b], m = bucketcnt[b];
    for (unsigned j = t; j < m; j += 1024) {
        unsigned e = entries[base + j];
        if (j < BCAP) se[j] = e;
        atomicAdd(&cnt[e >> 24], 1u);
    }
    __syncthreads();
    if (t < 256) sc[t] = cnt[t];
    __syncthreads();
    for (int s = 1; s < 256; s <<= 1) {
        unsigned a = (t < 256 && t >= s) ? sc[t - s] : 0u;
        __syncthreads();
        if (t < 256) sc[t] += a;
        __syncthreads();
    }
    if (t < 256) {
        unsigned excl = sc[t] - cnt[t];
        cur[t] = excl;
        int node = b * 256 + t;
        if (node < n) {
            rs_deg[node] = make_uint2(base + excl, cnt[t]);
            dinv[node] = cnt[t] ? rsqrtf((float)cnt[t]) : 0.f;
        }
    }
    __syncthreads();
    for (unsigned j = t; j < m; j += 1024) {
        unsigned e = (j < BCAP) ? se[j] : entries[base + j];
        unsigned pos = atomicAdd(&cur[e >> 24], 1u);
        entries[base + pos] = e & 0xFFFFFF;
    }
}

// ---------------- proj1: register-blocked; P0 = x@W1[0], P1s = (x@W1[1])*dinv ----
__global__ __launch_bounds__(256) void proj1_kernel(const float* __restrict__ x,
                                                    const float* __restrict__ W1,
                                                    const float* __restrict__ dinv,
                                                    float* __restrict__ P0,
                                                    float* __restrict__ P1s, int n) {
    __shared__ float xs[64 * 132];
    __shared__ float wt[32 * 132];
    int t = threadIdx.x;
    int base = blockIdx.x * 64;
    for (int idx = t; idx < 32 * 128; idx += 256) {
        int j = idx >> 7, k = idx & 127;
        int r = (j & 7) * 4 + (j >> 3);
        wt[r * 132 + k] = W1[((j >> 4) ? 2048 : 0) + k * 16 + (j & 15)];
    }
    for (int idx = t; idx < 2048; idx += 256) {
        int row = idx >> 5, c4 = idx & 31;
        int node = base + row;
        float4 v = make_float4(0.f, 0.f, 0.f, 0.f);
        if (node < n) v = *(const float4*)&x[(size_t)node * 128 + c4 * 4];
        *(float4*)&xs[row * 132 + c4 * 4] = v;
    }
    __syncthreads();
    int nl = t >> 2, q = t & 3;
    int node = base + nl;
    float acc[8] = {0.f, 0.f, 0.f, 0.f, 0.f, 0.f, 0.f, 0.f};
    const float* xr = xs + nl * 132;
    const float* wb = wt + q * 132;
#pragma unroll 4
    for (int kb = 0; kb < 32; ++kb) {
        float4 xv = *(const float4*)&xr[kb * 4];
#pragma unroll
        for (int jj = 0; jj < 8; ++jj) {
            float4 wv = *(const float4*)&wb[jj * 4 * 132 + kb * 4];
            acc[jj] += xv.x * wv.x + xv.y * wv.y + xv.z * wv.z + xv.w * wv.w;
        }
    }
    if (node >= n) return;
    if (q < 2) {
        *(float4*)&P0[(size_t)node * 16 + q * 8]     = make_float4(acc[0], acc[1], acc[2], acc[3]);
        *(float4*)&P0[(size_t)node * 16 + q * 8 + 4] = make_float4(acc[4], acc[5], acc[6], acc[7]);
    } else {
        float dr = dinv[node];
        int o = (q - 2) * 8;
        *(float4*)&P1s[(size_t)node * 16 + o]     = make_float4(acc[0]*dr, acc[1]*dr, acc[2]*dr, acc[3]*dr);
        *(float4*)&P1s[(size_t)node * 16 + o + 4] = make_float4(acc[4]*dr, acc[5]*dr, acc[6]*dr, acc[7]*dr);
    }
}

// ---------------- agg1: wave-per-node segment sum + relu epilogue ----------------
__global__ __launch_bounds__(256) void agg1_kernel(const uint2* __restrict__ rs_deg,
                                                   const unsigned* __restrict__ ecol,
                                                   const float* __restrict__ dinv,
                                                   const float* __restrict__ P1s,
                                                   const float* __restrict__ b1,
                                                   float* __restrict__ H,   // in: P0, out: h
                                                   float* __restrict__ HS, int n) {
    int wave = threadIdx.x >> 6, lane = threadIdx.x & 63;
    int node = blockIdx.x * 4 + wave;
    if (node >= n) return;
    int f = lane & 15, slot = lane >> 4;
    uint2 rd = rs_deg[node];
    float s = 0.f;
    unsigned j = slot, d = rd.y;
    for (; j + 12 < d; j += 16) {
        unsigned c0 = ecol[rd.x + j];
        unsigned c1 = ecol[rd.x + j + 4];
        unsigned c2 = ecol[rd.x + j + 8];
        unsigned c3 = ecol[rd.x + j + 12];
        s += P1s[(size_t)c0 * 16 + f] + P1s[(size_t)c1 * 16 + f]
           + P1s[(size_t)c2 * 16 + f] + P1s[(size_t)c3 * 16 + f];
    }
    for (; j < d; j += 4) s += P1s[(size_t)ecol[rd.x + j] * 16 + f];
    s += __shfl_xor(s, 16);
    s += __shfl_xor(s, 32);
    if (slot == 0) {
        float dr = dinv[node];
        float v = H[(size_t)node * 16 + f] - dr * s + b1[f];
        v = fmaxf(v, 0.f);
        H[(size_t)node * 16 + f] = v;
        HS[(size_t)node * 16 + f] = v * dr;
    }
}

// ---------------- agg2: wave-per-node gather; T2 = -dinv * sum(HS[c]) ----------------
__global__ __launch_bounds__(256) void agg2_kernel(const uint2* __restrict__ rs_deg,
                                                   const unsigned* __restrict__ ecol,
                                                   const float* __restrict__ dinv,
                                                   const float* __restrict__ HS,
                                                   float* __restrict__ T2, int n) {
    int wave = threadIdx.x >> 6, lane = threadIdx.x & 63;
    int node = blockIdx.x * 4 + wave;
    if (node >= n) return;
    int f = lane & 15, slot = lane >> 4;
    uint2 rd = rs_deg[node];
    float s = 0.f;
    unsigned j = slot, d = rd.y;
    for (; j + 12 < d; j += 16) {
        unsigned c0 = ecol[rd.x + j];
        unsigned c1 = ecol[rd.x + j + 4];
        unsigned c2 = ecol[rd.x + j + 8];
        unsigned c3 = ecol[rd.x + j + 12];
        s += HS[(size_t)c0 * 16 + f] + HS[(size_t)c1 * 16 + f]
           + HS[(size_t)c2 * 16 + f] + HS[(size_t)c3 * 16 + f];
    }
    for (; j < d; j += 4) s += HS[(size_t)ecol[rd.x + j] * 16 + f];
    s += __shfl_xor(s, 16);
    s += __shfl_xor(s, 32);
    if (slot == 0) T2[(size_t)node * 16 + f] = -dinv[node] * s;
}

// ---------------- out GEMM + log_softmax ----------------
// 32 nodes/block, 8 nodes/wave. W2 columns (j=lane, j=lane+64) live in 64 VGPRs,
// amortized over 8 nodes. h/t read as wave-uniform broadcast loads (no gathers).
__global__ __launch_bounds__(256) void out_gemm_kernel(const float* __restrict__ H,
                                                       const float* __restrict__ T2,
                                                       const float* __restrict__ W2,
                                                       const float* __restrict__ b2,
                                                       float* __restrict__ out, int n) {
    int wl = threadIdx.x >> 6, lane = threadIdx.x & 63;
    int nbase = blockIdx.x * 32 + wl * 8;

    float w00[16], w01[16], w10[16], w11[16];
#pragma unroll
    for (int k = 0; k < 16; ++k) {
        w00[k] = W2[k * 128 + lane];
        w01[k] = W2[2048 + k * 128 + lane];
        w10[k] = W2[k * 128 + lane + 64];
        w11[k] = W2[2048 + k * 128 + lane + 64];
    }
    float bb0 = b2[lane], bb1 = b2[lane + 64];

#pragma unroll 1
    for (int i = 0; i < 8; ++i) {
        int node = __builtin_amdgcn_readfirstlane(nbase + i);
        if (node >= n) return;
        const float* hp = H + (size_t)node * 16;
        const float* tp = T2 + (size_t)node * 16;
        float4 h0 = *(const float4*)&hp[0];
        float4 h1 = *(const float4*)&hp[4];
        float4 h2 = *(const float4*)&hp[8];
        float4 h3 = *(const float4*)&hp[12];
        float4 t0 = *(const float4*)&tp[0];
        float4 t1 = *(const float4*)&tp[4];
        float4 t2 = *(const float4*)&tp[8];
        float4 t3 = *(const float4*)&tp[12];
        float hv[16] = {h0.x,h0.y,h0.z,h0.w, h1.x,h1.y,h1.z,h1.w,
                        h2.x,h2.y,h2.z,h2.w, h3.x,h3.y,h3.z,h3.w};
        float tv[16] = {t0.x,t0.y,t0.z,t0.w, t1.x,t1.y,t1.z,t1.w,
                        t2.x,t2.y,t2.z,t2.w, t3.x,t3.y,t3.z,t3.w};
        float o0 = bb0, o1 = bb1;
#pragma unroll
        for (int k = 0; k < 16; ++k) {
            o0 += hv[k] * w00[k] + tv[k] * w01[k];
            o1 += hv[k] * w10[k] + tv[k] * w11[k];
        }
        float mx = fmaxf(o0, o1);
#pragma unroll
        for (int st = 1; st < 64; st <<= 1) mx = fmaxf(mx, __shfl_xor(mx, st));
        float ssum = expf(o0 - mx) + expf(o1 - mx);
#pragma unroll
        for (int st = 1; st < 64; st <<= 1) ssum += __shfl_xor(ssum, st);
        float lse = mx + logf(ssum);
        out[(size_t)node * 128 + lane]      = o0 - lse;
        out[(size_t)node * 128 + lane + 64] = o1 - lse;
    }
}

extern "C" void kernel_launch(void* const* d_in, const int* in_sizes, int n_in,
                              void* d_out, int out_size, void* d_ws, size_t ws_size,
                              hipStream_t stream) {
    const float* x  = (const float*)d_in[0];
    const int*   ei = (const int*)d_in[1];
    const float* W1 = (const float*)d_in[2];
    const float* b1 = (const float*)d_in[3];
    const float* W2 = (const float*)d_in[4];
    const float* b2 = (const float*)d_in[5];
    float* out = (float*)d_out;

    const int n = N_NODES, E = N_EDGES;
    const int* row = ei;
    const int* col = ei + E;

    // workspace layout (4B units); NPAD = 391*256 = 100096
    const size_t NPAD = 100096;
    unsigned* bucketcnt  = (unsigned*)d_ws;              // 512
    unsigned* bucketbase = bucketcnt + 512;              // 512
    unsigned* bucketcur  = bucketbase + 512;             // 512
    uint2*    rs_deg     = (uint2*)(bucketcur + 512);    // NPAD uint2
    float*    dinv       = (float*)(rs_deg + NPAD);      // NPAD
    unsigned* entries    = (unsigned*)(dinv + NPAD);     // E (packed, then col-only CSR)
    float*    P0         = (float*)(entries + E);        // NPAD*16 (becomes H in-place)
    float*    P1s        = P0 + NPAD * 16;               // NPAD*16 (dead after agg1 -> T2)
    float*    HS         = P1s + NPAD * 16;              // NPAD*16
    float*    T2         = P1s;                          // alias

    hipMemsetAsync(bucketcnt, 0, 512 * sizeof(unsigned), stream);

    bhist_kernel<<<NBKT, 256, 0, stream>>>(row, bucketcnt, E);
    bscan_kernel<<<1, 512, 0, stream>>>(bucketcnt, bucketbase, bucketcur);
    part_kernel<<<NBKT, 256, 0, stream>>>(row, col, bucketcur, entries, E);
    csr_kernel<<<NBKT, 1024, 0, stream>>>(bucketbase, bucketcnt, entries, rs_deg, dinv, n);
    proj1_kernel<<<(n + 63) / 64, 256, 0, stream>>>(x, W1, dinv, P0, P1s, n);
    agg1_kernel<<<(n + 3) / 4, 256, 0, stream>>>(rs_deg, entries, dinv, P1s, b1, P0, HS, n);
    agg2_kernel<<<(n + 3) / 4, 256, 0, stream>>>(rs_deg, entries, dinv, HS, T2, n);
    out_gemm_kernel<<<(n + 31) / 32, 256, 0, stream>>>(P0, T2, W2, b2, out, n);
}